// Round 18
// baseline (294.858 us; speedup 1.0000x reference)
//
#include <hip/hip_runtime.h>
#include <math.h>

namespace {
constexpr int B = 2;
constexpr int N = 16384;
constexpr int M = 4096;
constexpr int TQ = 64;              // lanes per query group = full wave
constexpr int BLOCK = 1024;         // 16 waves/block
constexpr int Q = 4;                // queries per wave
constexpr int GROUPS = BLOCK / TQ;  // 16 waves/block
constexpr int QPB = GROUPS * Q;     // 64 queries/block -> 512 blocks = 2/CU
constexpr int NB = 4;               // batches of 16 candidates per lane
constexpr int CAP = 48;             // per-query collect capacity
constexpr int CAPW = 256;           // per-wave worklist capacity
}

typedef float v2f __attribute__((ext_vector_type(2)));

// LDS candidate record viewed as two VGPR pairs: (x,y) and (z,w=|s|^2).
struct __attribute__((aligned(16))) S2 { v2f xy; v2f zw; };

// Shifted squared distance for TWO queries at once via packed FP32 VOP3P.
// Slot q = fma(m2z_q, z, fma(m2y_q, y, fma(m2x_q, x, w))). (R12-validated.)
// Values shifted by -|p_q|^2: comparable ONLY within a query.
__device__ __forceinline__ v2f d2pair(S2 s, v2f m2x, v2f m2y, v2f m2z) {
  v2f acc;
  asm("v_pk_fma_f32 %0, %1, %2, %3 op_sel:[0,0,1] op_sel_hi:[0,1,1]"
      : "=v"(acc) : "v"(s.xy), "v"(m2x), "v"(s.zw));
  asm("v_pk_fma_f32 %0, %1, %2, %0 op_sel:[1,0,0] op_sel_hi:[1,1,1]"
      : "+v"(acc) : "v"(s.xy), "v"(m2y));
  asm("v_pk_fma_f32 %0, %1, %2, %0 op_sel:[0,0,0] op_sel_hi:[0,1,1]"
      : "+v"(acc) : "v"(s.zw), "v"(m2z));
  return acc;
}

// Scalar twin of d2pair's per-slot sequence — bit-exact (validated R12–R17).
__device__ __forceinline__ float d2of(const float4 s, float m2x, float m2y, float m2z) {
  return fmaf(m2z, s.z, fmaf(m2y, s.y, fmaf(m2x, s.x, s.w)));
}

// |s|^2 — the ONE canonical sequence, used both in staging and in the
// odd-wave global path so both paths produce bit-identical S2 records.
__device__ __forceinline__ float wof(float x, float y, float z) {
  return fmaf(z, z, fmaf(y, y, x * x));
}

// 78 KiB LDS/block, <=64 VGPR -> 2 blocks/CU, 32 waves/CU = 8 waves/SIMD
__global__ __launch_bounds__(BLOCK, 8) void voroloss_kernel(
    const float* __restrict__ points,    // [B, N, 3]
    const float* __restrict__ spoints,   // [B, M, 3]
    float* __restrict__ out)             // [B, N]
{
  __shared__ float4 s4[M];                                    // 64 KiB
  __shared__ unsigned short wl_lds[GROUPS][CAPW];             // 8 KiB
  __shared__ __align__(16) unsigned short buf[QPB][CAP];      // 6 KiB

  const int blocks_per_batch = N / QPB;      // 256
  const int b = blockIdx.x / blocks_per_batch;
  const int tile = blockIdx.x % blocks_per_batch;
  const int tid = (int)threadIdx.x;
  const int wl = tid & 63;
  const int g = tid >> 6;
  const bool scanGlobal = (g & 1) != 0;      // odd waves scan via L1/L2

  const float* sp = spoints + (size_t)b * M * 3;
  for (int j = tid; j < M; j += BLOCK) {
    float x = sp[j * 3 + 0], y = sp[j * 3 + 1], z = sp[j * 3 + 2];
    s4[j] = make_float4(x, y, z, wof(x, y, z));
  }
  __syncthreads();
  const S2* s2 = (const S2*)s4;

  float m2x[Q], m2y[Q], m2z[Q];
#pragma unroll
  for (int q = 0; q < Q; ++q) {
    int n = tile * QPB + q * GROUPS + g;     // uniform per wave
    m2x[q] = -2.0f * points[((size_t)b * N + n) * 3 + 0];
    m2y[q] = -2.0f * points[((size_t)b * N + n) * 3 + 1];
    m2z[q] = -2.0f * points[((size_t)b * N + n) * 3 + 2];
  }
  v2f bmx[2], bmy[2], bmz[2];
#pragma unroll
  for (int p = 0; p < 2; ++p) {
    bmx[p].x = m2x[2 * p]; bmx[p].y = m2x[2 * p + 1];
    bmy[p].x = m2y[2 * p]; bmy[p].y = m2y[2 * p + 1];
    bmz[p].x = m2z[2 * p]; bmz[p].y = m2z[2 * p + 1];
  }

  // ---- Phase A: per-query batch minima over NB=4 batches of 16 cands.
  // Even waves read LDS; odd waves read global (L2-resident, 48 KB) and
  // rebuild the BIT-IDENTICAL S2 via wof(). Splits A-read traffic across
  // the DS and TA pipes (DS was the co-limiter at R15/R17).
  v2f bm2[2][NB];
#pragma unroll
  for (int p = 0; p < 2; ++p)
#pragma unroll
    for (int bi = 0; bi < NB; ++bi) { bm2[p][bi].x = INFINITY; bm2[p][bi].y = INFINITY; }

#pragma unroll
  for (int bi = 0; bi < NB; ++bi) {
#pragma unroll
    for (int hf = 0; hf < 4; ++hf) {
      S2 sv[4];
      if (scanGlobal) {
#pragma unroll
        for (int c = 0; c < 4; ++c) {
          const float* pp = sp + ((bi * 16 + hf * 4 + c) * TQ + wl) * 3;
          float x = pp[0], y = pp[1], z = pp[2];
          sv[c].xy.x = x; sv[c].xy.y = y;
          sv[c].zw.x = z; sv[c].zw.y = wof(x, y, z);
        }
      } else {
#pragma unroll
        for (int c = 0; c < 4; ++c) sv[c] = s2[(bi * 16 + hf * 4 + c) * TQ + wl];
      }
#pragma unroll
      for (int p = 0; p < 2; ++p) {
        v2f a0 = d2pair(sv[0], bmx[p], bmy[p], bmz[p]);
        v2f a1 = d2pair(sv[1], bmx[p], bmy[p], bmz[p]);
        v2f a2 = d2pair(sv[2], bmx[p], bmy[p], bmz[p]);
        v2f a3 = d2pair(sv[3], bmx[p], bmy[p], bmz[p]);
        float tx = fminf(fminf(a0.x, a1.x), a2.x);            // v_min3
        bm2[p][bi].x = fminf(fminf(tx, a3.x), bm2[p][bi].x);  // v_min3
        float ty = fminf(fminf(a0.y, a1.y), a2.y);
        bm2[p][bi].y = fminf(fminf(ty, a3.y), bm2[p][bi].y);
      }
    }
  }
  float t0[Q];
#pragma unroll
  for (int p = 0; p < 2; ++p) {
    v2f m = bm2[p][0];
#pragma unroll
    for (int bi = 1; bi < NB; ++bi) {
      m.x = fminf(m.x, bm2[p][bi].x);
      m.y = fminf(m.y, bm2[p][bi].y);
    }
    t0[2 * p] = m.x; t0[2 * p + 1] = m.y;
  }

  // ---- theta: 11th smallest of 32 pair-minima per query (sound upper bound
  // on the true 11th smallest; within-query so the shift cancels).
  const int h = wl & 31;
  bool km[15];
  {
    int st = 0;
#pragma unroll
    for (int k = 2; k <= 32; k <<= 1)
#pragma unroll
      for (int j = 16; j > 0; j >>= 1)
        if (j < k) {
          bool up = (h & k) == 0;
          bool lower = (h & j) == 0;
          km[st++] = (lower == up);
        }
  }
  float theta[Q];
#pragma unroll
  for (int qp = 0; qp < Q; qp += 2) {
    float a0 = fminf(t0[qp],     __shfl_xor(t0[qp],     32));
    float a1 = fminf(t0[qp + 1], __shfl_xor(t0[qp + 1], 32));
    float x = (wl < 32) ? a0 : a1;
    int st = 0;
#pragma unroll
    for (int k = 2; k <= 32; k <<= 1)
#pragma unroll
      for (int j = 16; j > 0; j >>= 1)
        if (j < k) {
          float o = __shfl_xor(x, j);
          x = km[st++] ? fminf(x, o) : fmaxf(x, o);
        }
    theta[qp]     = __shfl(x, 10, 64);
    theta[qp + 1] = __shfl(x, 42, 64);
  }

  // ---- Worklist: batches with ANY per-query hit (within-query comparison).
  int wcnt = 0;
#pragma unroll
  for (int bi = 0; bi < NB; ++bi) {
    bool hit = (bm2[0][bi].x <= theta[0]) || (bm2[0][bi].y <= theta[1]) ||
               (bm2[1][bi].x <= theta[2]) || (bm2[1][bi].y <= theta[3]);
    unsigned long long mask = __ballot(hit);
    if (mask != 0) {
      if (hit) {
        unsigned int lo = __builtin_amdgcn_mbcnt_lo((unsigned int)mask, 0u);
        unsigned int pr = __builtin_amdgcn_mbcnt_hi((unsigned int)(mask >> 32), lo);
        int pos = wcnt + (int)pr;
        if (pos < CAPW) wl_lds[g][pos] = (unsigned short)((bi << 6) | wl);
      }
      wcnt += (int)__popcll(mask);
    }
  }
  wcnt = wcnt < CAPW ? wcnt : CAPW;

  // ---- Phase B-lite: re-evaluate worklist batches from LDS (bit-exact
  // d2pair). Per-lane 16-bit hit masks, one ffbl flush loop per query.
  int cnt[Q];
#pragma unroll
  for (int q = 0; q < Q; ++q) cnt[q] = 0;

  for (int base = 0; base < wcnt; base += 64) {
    int ii = base + wl;
    bool val = ii < wcnt;
    int e = wl_lds[g][val ? ii : 0];
    int bi = e >> 6, src = e & 63;

    unsigned hm[Q] = {0u, 0u, 0u, 0u};
#pragma unroll
    for (int hf = 0; hf < 4; ++hf) {
      S2 sv[4];
#pragma unroll
      for (int c = 0; c < 4; ++c) sv[c] = s2[(bi * 16 + hf * 4 + c) * TQ + src];
#pragma unroll
      for (int p = 0; p < 2; ++p) {
#pragma unroll
        for (int c = 0; c < 4; ++c) {
          v2f acc = d2pair(sv[c], bmx[p], bmy[p], bmz[p]);
          unsigned bit = 1u << (hf * 4 + c);
          hm[2 * p]     |= (acc.x <= theta[2 * p])     ? bit : 0u;
          hm[2 * p + 1] |= (acc.y <= theta[2 * p + 1]) ? bit : 0u;
        }
      }
    }
    if (!val) { hm[0] = 0u; hm[1] = 0u; hm[2] = 0u; hm[3] = 0u; }

#pragma unroll
    for (int q = 0; q < Q; ++q) {
      const int qq = q * GROUPS + g;
      unsigned m = hm[q];
      unsigned long long bmk = __ballot(m != 0u);
      while (bmk) {                       // uniform loop; ~1 iteration
        bool have = m != 0u;
        int k = __ffs(m) - 1;
        unsigned int lo = __builtin_amdgcn_mbcnt_lo((unsigned int)bmk, 0u);
        unsigned int pr = __builtin_amdgcn_mbcnt_hi((unsigned int)(bmk >> 32), lo);
        int pos = cnt[q] + (int)pr;
        if (have && pos < CAP)
          buf[qq][pos] = (unsigned short)((bi * 16 + k) * TQ + src);
        cnt[q] += (int)__popcll(bmk);
        m &= m - 1u;
        bmk = __ballot(m != 0u);
      }
    }
  }

  // ---- Phase C: exact selection (lex (d2,idx) = stable top_k). Ranks via
  // uniform broadcast reads of indices + s4 and bit-exact d2of.
#pragma unroll
  for (int q = 0; q < Q; ++q) {
    const int qq = q * GROUPS + g;
    int c = cnt[q];
    c = c < CAP ? c : CAP;

    bool v = wl < c;
    int ide = (int)buf[qq][v ? wl : 0];
    float4 se = s4[ide];
    float d2e = v ? d2of(se, m2x[q], m2y[q], m2z[q]) : INFINITY;
    ide = v ? ide : 0x7fffffff;

    int rank = 0;
    for (int f0 = 0; f0 < c; f0 += 8) {   // one uniform b128 = 8 indices
      ushort idx8[8];
      *(int4*)idx8 = *(const int4*)&buf[qq][f0];
#pragma unroll
      for (int t = 0; t < 8; ++t) {
        int f = f0 + t;
        int jf = (int)idx8[t];
        float4 sf = s4[jf];               // uniform address -> broadcast read
        float df = d2of(sf, m2x[q], m2y[q], m2z[q]);
        bool less = (df < d2e) || (df == d2e && jf < ide);
        rank += (f < c && less) ? 1 : 0;
      }
    }

    // center = rank 0 (exists, unique): ballot + shfl its index.
    unsigned long long cb = __ballot(v && rank == 0);
    int cl = (int)__builtin_ctzll(cb);
    int ci = __shfl(ide, cl, 64);
    float4 cc = s4[ci];
    float px = -0.5f * m2x[q], py = -0.5f * m2y[q], pz = -0.5f * m2z[q];
    float vx = px - cc.x, vy = py - cc.y, vz = pz - cc.z;

    // edges = ranks 1..10 (exactly 10 since c >= 11).
    bool isedge = v && (rank >= 1) && (rank <= 10);
    float ex = se.x - cc.x, ey = se.y - cc.y, ez = se.z - cc.z;
    float el2 = ex * ex;
    el2 = fmaf(ey, ey, el2);
    el2 = fmaf(ez, ez, el2);
    float dv = vx * ex;
    dv = fmaf(vy, ey, dv);
    dv = fmaf(vz, ez, dv);
    float tt = fmaf(-0.5f, el2, dv);
    float sq = tt * tt * __builtin_amdgcn_rcpf(el2);
    float best = isedge ? sq : INFINITY;
#pragma unroll
    for (int lvl = 1; lvl <= 32; lvl <<= 1) {
      best = fminf(best, __shfl_xor(best, lvl));
    }
    if (wl == 0) out[(size_t)b * N + (tile * QPB + q * GROUPS + g)] = best;
  }
}

extern "C" void kernel_launch(void* const* d_in, const int* in_sizes, int n_in,
                              void* d_out, int out_size, void* d_ws, size_t ws_size,
                              hipStream_t stream) {
  const float* points = (const float*)d_in[0];
  const float* spoints = (const float*)d_in[1];
  float* out = (float*)d_out;
  (void)in_sizes; (void)n_in; (void)out_size; (void)d_ws; (void)ws_size;
  voroloss_kernel<<<dim3(B * (N / QPB)), dim3(BLOCK), 0, stream>>>(points, spoints, out);
}

// Round 19
// 101.958 us; speedup vs baseline: 2.8920x; 2.8920x over previous
//
#include <hip/hip_runtime.h>
#include <math.h>

namespace {
constexpr int B = 2;
constexpr int N = 16384;
constexpr int M = 4096;
constexpr int TQ = 64;              // lanes per query group = full wave
constexpr int BLOCK = 1024;         // 16 waves/block
constexpr int Q = 8;                // queries per wave
constexpr int GROUPS = BLOCK / TQ;  // 16 waves/block
constexpr int QPB = GROUPS * Q;     // 128 queries/block -> 256 blocks = 1/CU
constexpr int NB = 4;               // batches of 16 candidates per lane
constexpr int CAP = 48;             // per-query collect capacity
constexpr int CAPW = 256;           // per-wave worklist capacity
}

typedef float v2f __attribute__((ext_vector_type(2)));

// LDS candidate record viewed as two VGPR pairs: (x,y) and (z,w=|s|^2).
struct __attribute__((aligned(16))) S2 { v2f xy; v2f zw; };

// Shifted squared distance for TWO queries at once via packed FP32 VOP3P.
// Slot q = fma(m2z_q, z, fma(m2y_q, y, fma(m2x_q, x, w))). (R12-validated.)
// Values shifted by -|p_q|^2: comparable ONLY within a query.
__device__ __forceinline__ v2f d2pair(S2 s, v2f m2x, v2f m2y, v2f m2z) {
  v2f acc;
  asm("v_pk_fma_f32 %0, %1, %2, %3 op_sel:[0,0,1] op_sel_hi:[0,1,1]"
      : "=v"(acc) : "v"(s.xy), "v"(m2x), "v"(s.zw));
  asm("v_pk_fma_f32 %0, %1, %2, %0 op_sel:[1,0,0] op_sel_hi:[1,1,1]"
      : "+v"(acc) : "v"(s.xy), "v"(m2y));
  asm("v_pk_fma_f32 %0, %1, %2, %0 op_sel:[0,0,0] op_sel_hi:[0,1,1]"
      : "+v"(acc) : "v"(s.zw), "v"(m2z));
  return acc;
}

// Scalar twin of d2pair's per-slot sequence — bit-exact (validated R12–R17).
__device__ __forceinline__ float d2of(const float4 s, float m2x, float m2y, float m2z) {
  return fmaf(m2z, s.z, fmaf(m2y, s.y, fmaf(m2x, s.x, s.w)));
}

// 84 KiB LDS/block -> 1 block/CU; 16 waves/CU = 4 waves/SIMD; VGPR cap 128.
__global__ __launch_bounds__(BLOCK, 4) void voroloss_kernel(
    const float* __restrict__ points,    // [B, N, 3]
    const float* __restrict__ spoints,   // [B, M, 3]
    float* __restrict__ out)             // [B, N]
{
  __shared__ float4 s4[M];                                    // 64 KiB
  __shared__ unsigned short wl_lds[GROUPS][CAPW];             // 8 KiB
  __shared__ __align__(16) unsigned short buf[QPB][CAP];      // 12 KiB

  const int blocks_per_batch = N / QPB;      // 128
  const int b = blockIdx.x / blocks_per_batch;
  const int tile = blockIdx.x % blocks_per_batch;
  const int tid = (int)threadIdx.x;
  const int wl = tid & 63;
  const int g = tid >> 6;

  const float* sp = spoints + (size_t)b * M * 3;
  for (int j = tid; j < M; j += BLOCK) {
    float x = sp[j * 3 + 0], y = sp[j * 3 + 1], z = sp[j * 3 + 2];
    s4[j] = make_float4(x, y, z, x * x + y * y + z * z);
  }
  __syncthreads();
  const S2* s2 = (const S2*)s4;

  float m2x[Q], m2y[Q], m2z[Q];
#pragma unroll
  for (int q = 0; q < Q; ++q) {
    int n = tile * QPB + q * GROUPS + g;     // uniform per wave
    m2x[q] = -2.0f * points[((size_t)b * N + n) * 3 + 0];
    m2y[q] = -2.0f * points[((size_t)b * N + n) * 3 + 1];
    m2z[q] = -2.0f * points[((size_t)b * N + n) * 3 + 2];
  }
  v2f bmx[Q / 2], bmy[Q / 2], bmz[Q / 2];
#pragma unroll
  for (int p = 0; p < Q / 2; ++p) {
    bmx[p].x = m2x[2 * p]; bmx[p].y = m2x[2 * p + 1];
    bmy[p].x = m2y[2 * p]; bmy[p].y = m2y[2 * p + 1];
    bmz[p].x = m2z[2 * p]; bmz[p].y = m2z[2 * p + 1];
  }

  // ---- Phase A: per-query batch minima over NB=4 batches of 16 cands.
  // Single LDS path (R18's dual global/LDS path spilled to scratch).
  v2f bm2[Q / 2][NB];
#pragma unroll
  for (int p = 0; p < Q / 2; ++p)
#pragma unroll
    for (int bi = 0; bi < NB; ++bi) { bm2[p][bi].x = INFINITY; bm2[p][bi].y = INFINITY; }

#pragma unroll
  for (int bi = 0; bi < NB; ++bi) {
#pragma unroll
    for (int hf = 0; hf < 4; ++hf) {
      S2 sv[4];
#pragma unroll
      for (int c = 0; c < 4; ++c) sv[c] = s2[(bi * 16 + hf * 4 + c) * TQ + wl];
#pragma unroll
      for (int p = 0; p < Q / 2; ++p) {
        v2f a0 = d2pair(sv[0], bmx[p], bmy[p], bmz[p]);
        v2f a1 = d2pair(sv[1], bmx[p], bmy[p], bmz[p]);
        v2f a2 = d2pair(sv[2], bmx[p], bmy[p], bmz[p]);
        v2f a3 = d2pair(sv[3], bmx[p], bmy[p], bmz[p]);
        float tx = fminf(fminf(a0.x, a1.x), a2.x);            // v_min3
        bm2[p][bi].x = fminf(fminf(tx, a3.x), bm2[p][bi].x);  // v_min3
        float ty = fminf(fminf(a0.y, a1.y), a2.y);
        bm2[p][bi].y = fminf(fminf(ty, a3.y), bm2[p][bi].y);
      }
    }
  }
  float t0[Q];
#pragma unroll
  for (int p = 0; p < Q / 2; ++p) {
    v2f m = bm2[p][0];
#pragma unroll
    for (int bi = 1; bi < NB; ++bi) {
      m.x = fminf(m.x, bm2[p][bi].x);
      m.y = fminf(m.y, bm2[p][bi].y);
    }
    t0[2 * p] = m.x; t0[2 * p + 1] = m.y;
  }

  // ---- theta: 11th smallest of 32 pair-minima per query (sound upper bound
  // on the true 11th smallest; within-query so the shift cancels).
  const int h = wl & 31;
  bool km[15];
  {
    int st = 0;
#pragma unroll
    for (int k = 2; k <= 32; k <<= 1)
#pragma unroll
      for (int j = 16; j > 0; j >>= 1)
        if (j < k) {
          bool up = (h & k) == 0;
          bool lower = (h & j) == 0;
          km[st++] = (lower == up);
        }
  }
  float theta[Q];
#pragma unroll
  for (int qp = 0; qp < Q; qp += 2) {
    float a0 = fminf(t0[qp],     __shfl_xor(t0[qp],     32));
    float a1 = fminf(t0[qp + 1], __shfl_xor(t0[qp + 1], 32));
    float x = (wl < 32) ? a0 : a1;
    int st = 0;
#pragma unroll
    for (int k = 2; k <= 32; k <<= 1)
#pragma unroll
      for (int j = 16; j > 0; j >>= 1)
        if (j < k) {
          float o = __shfl_xor(x, j);
          x = km[st++] ? fminf(x, o) : fmaxf(x, o);
        }
    theta[qp]     = __shfl(x, 10, 64);
    theta[qp + 1] = __shfl(x, 42, 64);
  }

  // ---- Worklist: batches with ANY per-query hit (within-query comparison).
  int wcnt = 0;
#pragma unroll
  for (int bi = 0; bi < NB; ++bi) {
    bool hit = false;
#pragma unroll
    for (int p = 0; p < Q / 2; ++p) {
      hit = hit || (bm2[p][bi].x <= theta[2 * p]) || (bm2[p][bi].y <= theta[2 * p + 1]);
    }
    unsigned long long mask = __ballot(hit);
    if (mask != 0) {
      if (hit) {
        unsigned int lo = __builtin_amdgcn_mbcnt_lo((unsigned int)mask, 0u);
        unsigned int pr = __builtin_amdgcn_mbcnt_hi((unsigned int)(mask >> 32), lo);
        int pos = wcnt + (int)pr;
        if (pos < CAPW) wl_lds[g][pos] = (unsigned short)((bi << 6) | wl);
      }
      wcnt += (int)__popcll(mask);
    }
  }
  wcnt = wcnt < CAPW ? wcnt : CAPW;

  // ---- Phase B-lite: re-evaluate worklist batches. Per-lane 16-bit hit
  // masks, then one ffbl flush loop per query (usually 1 iteration).
  int cnt[Q];
#pragma unroll
  for (int q = 0; q < Q; ++q) cnt[q] = 0;

  for (int base = 0; base < wcnt; base += 64) {
    int ii = base + wl;
    bool val = ii < wcnt;
    int e = wl_lds[g][val ? ii : 0];
    int bi = e >> 6, src = e & 63;

    unsigned hm[Q];
#pragma unroll
    for (int q = 0; q < Q; ++q) hm[q] = 0u;
#pragma unroll
    for (int hf = 0; hf < 4; ++hf) {
      S2 sv[4];
#pragma unroll
      for (int c = 0; c < 4; ++c) sv[c] = s2[(bi * 16 + hf * 4 + c) * TQ + src];
#pragma unroll
      for (int p = 0; p < Q / 2; ++p) {
#pragma unroll
        for (int c = 0; c < 4; ++c) {
          v2f acc = d2pair(sv[c], bmx[p], bmy[p], bmz[p]);
          unsigned bit = 1u << (hf * 4 + c);
          hm[2 * p]     |= (acc.x <= theta[2 * p])     ? bit : 0u;
          hm[2 * p + 1] |= (acc.y <= theta[2 * p + 1]) ? bit : 0u;
        }
      }
    }
    if (!val) {
#pragma unroll
      for (int q = 0; q < Q; ++q) hm[q] = 0u;
    }

#pragma unroll
    for (int q = 0; q < Q; ++q) {
      const int qq = q * GROUPS + g;
      unsigned m = hm[q];
      unsigned long long bmk = __ballot(m != 0u);
      while (bmk) {                       // uniform loop; ~1 iteration
        bool have = m != 0u;
        int k = __ffs(m) - 1;
        unsigned int lo = __builtin_amdgcn_mbcnt_lo((unsigned int)bmk, 0u);
        unsigned int pr = __builtin_amdgcn_mbcnt_hi((unsigned int)(bmk >> 32), lo);
        int pos = cnt[q] + (int)pr;
        if (have && pos < CAP)
          buf[qq][pos] = (unsigned short)((bi * 16 + k) * TQ + src);
        cnt[q] += (int)__popcll(bmk);
        m &= m - 1u;
        bmk = __ballot(m != 0u);
      }
    }
  }

  // ---- Phase C: exact selection (lex (d2,idx) = stable top_k). Ranks via
  // uniform broadcast reads of indices + s4 and bit-exact d2of.
#pragma unroll
  for (int q = 0; q < Q; ++q) {
    const int qq = q * GROUPS + g;
    int c = cnt[q];
    c = c < CAP ? c : CAP;

    bool v = wl < c;
    int ide = (int)buf[qq][v ? wl : 0];
    float4 se = s4[ide];
    float d2e = v ? d2of(se, m2x[q], m2y[q], m2z[q]) : INFINITY;
    ide = v ? ide : 0x7fffffff;

    int rank = 0;
    for (int f0 = 0; f0 < c; f0 += 8) {   // one uniform b128 = 8 indices
      ushort idx8[8];
      *(int4*)idx8 = *(const int4*)&buf[qq][f0];
#pragma unroll
      for (int t = 0; t < 8; ++t) {
        int f = f0 + t;
        int jf = (int)idx8[t];
        float4 sf = s4[jf];               // uniform address -> broadcast read
        float df = d2of(sf, m2x[q], m2y[q], m2z[q]);
        bool less = (df < d2e) || (df == d2e && jf < ide);
        rank += (f < c && less) ? 1 : 0;
      }
    }

    // center = rank 0 (exists, unique): ballot + shfl its index.
    unsigned long long cb = __ballot(v && rank == 0);
    int cl = (int)__builtin_ctzll(cb);
    int ci = __shfl(ide, cl, 64);
    float4 cc = s4[ci];
    float px = -0.5f * m2x[q], py = -0.5f * m2y[q], pz = -0.5f * m2z[q];
    float vx = px - cc.x, vy = py - cc.y, vz = pz - cc.z;

    // edges = ranks 1..10 (exactly 10 since c >= 11).
    bool isedge = v && (rank >= 1) && (rank <= 10);
    float ex = se.x - cc.x, ey = se.y - cc.y, ez = se.z - cc.z;
    float el2 = ex * ex;
    el2 = fmaf(ey, ey, el2);
    el2 = fmaf(ez, ez, el2);
    float dv = vx * ex;
    dv = fmaf(vy, ey, dv);
    dv = fmaf(vz, ez, dv);
    float tt = fmaf(-0.5f, el2, dv);
    float sq = tt * tt * __builtin_amdgcn_rcpf(el2);
    float best = isedge ? sq : INFINITY;
#pragma unroll
    for (int lvl = 1; lvl <= 32; lvl <<= 1) {
      best = fminf(best, __shfl_xor(best, lvl));
    }
    if (wl == 0) out[(size_t)b * N + (tile * QPB + q * GROUPS + g)] = best;
  }
}

extern "C" void kernel_launch(void* const* d_in, const int* in_sizes, int n_in,
                              void* d_out, int out_size, void* d_ws, size_t ws_size,
                              hipStream_t stream) {
  const float* points = (const float*)d_in[0];
  const float* spoints = (const float*)d_in[1];
  float* out = (float*)d_out;
  (void)in_sizes; (void)n_in; (void)out_size; (void)d_ws; (void)ws_size;
  voroloss_kernel<<<dim3(B * (N / QPB)), dim3(BLOCK), 0, stream>>>(points, spoints, out);
}

// Round 20
// 84.762 us; speedup vs baseline: 3.4787x; 1.2029x over previous
//
#include <hip/hip_runtime.h>
#include <math.h>

namespace {
constexpr int B = 2;
constexpr int N = 16384;
constexpr int M = 4096;
constexpr int TQ = 64;              // lanes per query group = full wave
constexpr int BLOCK = 1024;         // 16 waves/block
constexpr int Q = 4;                // queries per wave
constexpr int GROUPS = BLOCK / TQ;  // 16 waves/block
constexpr int QPB = GROUPS * Q;     // 64 queries/block -> 512 blocks = 2/CU
constexpr int NB = 4;               // batches of 16 candidates per lane
constexpr int CAP = 48;             // per-query collect capacity
constexpr int CAPW = 256;           // per-wave worklist capacity
}

typedef float v2f __attribute__((ext_vector_type(2)));

// LDS candidate record viewed as two VGPR pairs: (x,y) and (z,w=|s|^2).
struct __attribute__((aligned(16))) S2 { v2f xy; v2f zw; };

// Shifted squared distance for TWO queries at once via packed FP32 VOP3P.
// Slot q = fma(m2z_q, z, fma(m2y_q, y, fma(m2x_q, x, w))). (R12-validated.)
// Values shifted by -|p_q|^2: comparable ONLY within a query.
__device__ __forceinline__ v2f d2pair(S2 s, v2f m2x, v2f m2y, v2f m2z) {
  v2f acc;
  asm("v_pk_fma_f32 %0, %1, %2, %3 op_sel:[0,0,1] op_sel_hi:[0,1,1]"
      : "=v"(acc) : "v"(s.xy), "v"(m2x), "v"(s.zw));
  asm("v_pk_fma_f32 %0, %1, %2, %0 op_sel:[1,0,0] op_sel_hi:[1,1,1]"
      : "+v"(acc) : "v"(s.xy), "v"(m2y));
  asm("v_pk_fma_f32 %0, %1, %2, %0 op_sel:[0,0,0] op_sel_hi:[0,1,1]"
      : "+v"(acc) : "v"(s.zw), "v"(m2z));
  return acc;
}

// Scalar twin of d2pair's per-slot sequence — bit-exact (validated R12–R17).
__device__ __forceinline__ float d2of(const float4 s, float m2x, float m2y, float m2z) {
  return fmaf(m2z, s.z, fmaf(m2y, s.y, fmaf(m2x, s.x, s.w)));
}

// 78 KiB LDS/block, <=64 VGPR -> 2 blocks/CU, 32 waves/CU = 8 waves/SIMD
__global__ __launch_bounds__(BLOCK, 8) void voroloss_kernel(
    const float* __restrict__ points,    // [B, N, 3]
    const float* __restrict__ spoints,   // [B, M, 3]
    float* __restrict__ out)             // [B, N]
{
  __shared__ float4 s4[M];                                    // 64 KiB
  __shared__ unsigned short wl_lds[GROUPS][CAPW];             // 8 KiB
  __shared__ __align__(16) unsigned short buf[QPB][CAP];      // 6 KiB

  const int blocks_per_batch = N / QPB;      // 256
  const int b = blockIdx.x / blocks_per_batch;
  const int tile = blockIdx.x % blocks_per_batch;
  const int tid = (int)threadIdx.x;
  const int wl = tid & 63;
  const int g = tid >> 6;

  const float* sp = spoints + (size_t)b * M * 3;
  for (int j = tid; j < M; j += BLOCK) {
    float x = sp[j * 3 + 0], y = sp[j * 3 + 1], z = sp[j * 3 + 2];
    s4[j] = make_float4(x, y, z, x * x + y * y + z * z);
  }
  __syncthreads();
  const S2* s2 = (const S2*)s4;

  float m2x[Q], m2y[Q], m2z[Q];
#pragma unroll
  for (int q = 0; q < Q; ++q) {
    int n = tile * QPB + q * GROUPS + g;     // uniform per wave
    m2x[q] = -2.0f * points[((size_t)b * N + n) * 3 + 0];
    m2y[q] = -2.0f * points[((size_t)b * N + n) * 3 + 1];
    m2z[q] = -2.0f * points[((size_t)b * N + n) * 3 + 2];
  }
  v2f bmx[2], bmy[2], bmz[2];
#pragma unroll
  for (int p = 0; p < 2; ++p) {
    bmx[p].x = m2x[2 * p]; bmx[p].y = m2x[2 * p + 1];
    bmy[p].x = m2y[2 * p]; bmy[p].y = m2y[2 * p + 1];
    bmz[p].x = m2z[2 * p]; bmz[p].y = m2z[2 * p + 1];
  }

  // ---- Phase A: per-query batch minima over NB=4 batches of 16 cands.
  v2f bm2[2][NB];
#pragma unroll
  for (int p = 0; p < 2; ++p)
#pragma unroll
    for (int bi = 0; bi < NB; ++bi) { bm2[p][bi].x = INFINITY; bm2[p][bi].y = INFINITY; }

#pragma unroll
  for (int bi = 0; bi < NB; ++bi) {
#pragma unroll
    for (int hf = 0; hf < 4; ++hf) {
      S2 sv[4];
#pragma unroll
      for (int c = 0; c < 4; ++c) sv[c] = s2[(bi * 16 + hf * 4 + c) * TQ + wl];
#pragma unroll
      for (int p = 0; p < 2; ++p) {
        v2f a0 = d2pair(sv[0], bmx[p], bmy[p], bmz[p]);
        v2f a1 = d2pair(sv[1], bmx[p], bmy[p], bmz[p]);
        v2f a2 = d2pair(sv[2], bmx[p], bmy[p], bmz[p]);
        v2f a3 = d2pair(sv[3], bmx[p], bmy[p], bmz[p]);
        float tx = fminf(fminf(a0.x, a1.x), a2.x);            // v_min3
        bm2[p][bi].x = fminf(fminf(tx, a3.x), bm2[p][bi].x);  // v_min3
        float ty = fminf(fminf(a0.y, a1.y), a2.y);
        bm2[p][bi].y = fminf(fminf(ty, a3.y), bm2[p][bi].y);
      }
    }
  }
  float t0[Q];
#pragma unroll
  for (int p = 0; p < 2; ++p) {
    v2f m = bm2[p][0];
#pragma unroll
    for (int bi = 1; bi < NB; ++bi) {
      m.x = fminf(m.x, bm2[p][bi].x);
      m.y = fminf(m.y, bm2[p][bi].y);
    }
    t0[2 * p] = m.x; t0[2 * p + 1] = m.y;
  }

  // ---- theta: 11th smallest of 32 pair-minima per query (sound upper bound
  // on the true 11th smallest; within-query so the shift cancels).
  const int h = wl & 31;
  bool km[15];
  {
    int st = 0;
#pragma unroll
    for (int k = 2; k <= 32; k <<= 1)
#pragma unroll
      for (int j = 16; j > 0; j >>= 1)
        if (j < k) {
          bool up = (h & k) == 0;
          bool lower = (h & j) == 0;
          km[st++] = (lower == up);
        }
  }
  float theta[Q];
#pragma unroll
  for (int qp = 0; qp < Q; qp += 2) {
    float a0 = fminf(t0[qp],     __shfl_xor(t0[qp],     32));
    float a1 = fminf(t0[qp + 1], __shfl_xor(t0[qp + 1], 32));
    float x = (wl < 32) ? a0 : a1;
    int st = 0;
#pragma unroll
    for (int k = 2; k <= 32; k <<= 1)
#pragma unroll
      for (int j = 16; j > 0; j >>= 1)
        if (j < k) {
          float o = __shfl_xor(x, j);
          x = km[st++] ? fminf(x, o) : fmaxf(x, o);
        }
    theta[qp]     = __shfl(x, 10, 64);
    theta[qp + 1] = __shfl(x, 42, 64);
  }

  // ---- Worklist: batches with ANY per-query hit (within-query comparison).
  int wcnt = 0;
#pragma unroll
  for (int bi = 0; bi < NB; ++bi) {
    bool hit = (bm2[0][bi].x <= theta[0]) || (bm2[0][bi].y <= theta[1]) ||
               (bm2[1][bi].x <= theta[2]) || (bm2[1][bi].y <= theta[3]);
    unsigned long long mask = __ballot(hit);
    if (mask != 0) {
      if (hit) {
        unsigned int lo = __builtin_amdgcn_mbcnt_lo((unsigned int)mask, 0u);
        unsigned int pr = __builtin_amdgcn_mbcnt_hi((unsigned int)(mask >> 32), lo);
        int pos = wcnt + (int)pr;
        if (pos < CAPW) wl_lds[g][pos] = (unsigned short)((bi << 6) | wl);
      }
      wcnt += (int)__popcll(mask);
    }
  }
  wcnt = wcnt < CAPW ? wcnt : CAPW;

  // ---- Phase B-lite: re-evaluate worklist batches. Per-lane 16-bit hit
  // masks, then one ffbl flush loop per query (usually 1 iteration).
  int cnt[Q];
#pragma unroll
  for (int q = 0; q < Q; ++q) cnt[q] = 0;

  for (int base = 0; base < wcnt; base += 64) {
    int ii = base + wl;
    bool val = ii < wcnt;
    int e = wl_lds[g][val ? ii : 0];
    int bi = e >> 6, src = e & 63;

    unsigned hm[Q] = {0u, 0u, 0u, 0u};
#pragma unroll
    for (int hf = 0; hf < 4; ++hf) {
      S2 sv[4];
#pragma unroll
      for (int c = 0; c < 4; ++c) sv[c] = s2[(bi * 16 + hf * 4 + c) * TQ + src];
#pragma unroll
      for (int p = 0; p < 2; ++p) {
#pragma unroll
        for (int c = 0; c < 4; ++c) {
          v2f acc = d2pair(sv[c], bmx[p], bmy[p], bmz[p]);
          unsigned bit = 1u << (hf * 4 + c);
          hm[2 * p]     |= (acc.x <= theta[2 * p])     ? bit : 0u;
          hm[2 * p + 1] |= (acc.y <= theta[2 * p + 1]) ? bit : 0u;
        }
      }
    }
    if (!val) { hm[0] = 0u; hm[1] = 0u; hm[2] = 0u; hm[3] = 0u; }

#pragma unroll
    for (int q = 0; q < Q; ++q) {
      const int qq = q * GROUPS + g;
      unsigned m = hm[q];
      unsigned long long bmk = __ballot(m != 0u);
      while (bmk) {                       // uniform loop; ~1 iteration
        bool have = m != 0u;
        int k = __ffs(m) - 1;
        unsigned int lo = __builtin_amdgcn_mbcnt_lo((unsigned int)bmk, 0u);
        unsigned int pr = __builtin_amdgcn_mbcnt_hi((unsigned int)(bmk >> 32), lo);
        int pos = cnt[q] + (int)pr;
        if (have && pos < CAP)
          buf[qq][pos] = (unsigned short)((bi * 16 + k) * TQ + src);
        cnt[q] += (int)__popcll(bmk);
        m &= m - 1u;
        bmk = __ballot(m != 0u);
      }
    }
  }

  // ---- Phase C: exact selection (lex (d2,idx) = stable top_k). Rank loop
  // broadcasts lane-f's key via v_readlane (VALU pipe, SGPR compare) —
  // ZERO DS ops in the rank loop (was ~18 b128/query = as much DS as the
  // whole Phase A scan; R15-shfl equivalent was bpermute = same DS pipe).
#pragma unroll
  for (int q = 0; q < Q; ++q) {
    const int qq = q * GROUPS + g;
    int c = cnt[q];
    c = c < CAP ? c : CAP;

    bool v = wl < c;
    int ide = (int)buf[qq][v ? wl : 0];
    float4 se = s4[ide];
    float d2e = v ? d2of(se, m2x[q], m2y[q], m2z[q]) : INFINITY;
    ide = v ? ide : 0x7fffffff;
    const int d2b = __float_as_int(d2e);

    int rank = 0;
    for (int f = 0; f < c; ++f) {         // f wave-uniform -> readlane->SGPR
      float df = __int_as_float(__builtin_amdgcn_readlane(d2b, f));
      int jf = __builtin_amdgcn_readlane(ide, f);
      rank += ((df < d2e) || (df == d2e && jf < ide)) ? 1 : 0;
    }

    // center = rank 0 (exists, unique): ballot + readlane its index.
    unsigned long long cb = __ballot(v && rank == 0);
    int cl = (int)__builtin_ctzll(cb);
    int ci = __builtin_amdgcn_readlane(ide, cl);
    float4 cc = s4[ci];
    float px = -0.5f * m2x[q], py = -0.5f * m2y[q], pz = -0.5f * m2z[q];
    float vx = px - cc.x, vy = py - cc.y, vz = pz - cc.z;

    // edges = ranks 1..10 (exactly 10 since c >= 11).
    bool isedge = v && (rank >= 1) && (rank <= 10);
    float ex = se.x - cc.x, ey = se.y - cc.y, ez = se.z - cc.z;
    float el2 = ex * ex;
    el2 = fmaf(ey, ey, el2);
    el2 = fmaf(ez, ez, el2);
    float dv = vx * ex;
    dv = fmaf(vy, ey, dv);
    dv = fmaf(vz, ez, dv);
    float tt = fmaf(-0.5f, el2, dv);
    float sq = tt * tt * __builtin_amdgcn_rcpf(el2);
    float best = isedge ? sq : INFINITY;
#pragma unroll
    for (int lvl = 1; lvl <= 32; lvl <<= 1) {
      best = fminf(best, __shfl_xor(best, lvl));
    }
    if (wl == 0) out[(size_t)b * N + (tile * QPB + q * GROUPS + g)] = best;
  }
}

extern "C" void kernel_launch(void* const* d_in, const int* in_sizes, int n_in,
                              void* d_out, int out_size, void* d_ws, size_t ws_size,
                              hipStream_t stream) {
  const float* points = (const float*)d_in[0];
  const float* spoints = (const float*)d_in[1];
  float* out = (float*)d_out;
  (void)in_sizes; (void)n_in; (void)out_size; (void)d_ws; (void)ws_size;
  voroloss_kernel<<<dim3(B * (N / QPB)), dim3(BLOCK), 0, stream>>>(points, spoints, out);
}